// Round 13
// baseline (1086.499 us; speedup 1.0000x reference)
//
#include <hip/hip_runtime.h>

// BendingEnergy: fused 19-point stencil + per-batch mean, LDS x-march v9.
// v6/v8 dataflow (each LDS row read ONCE per x-march; 20 units/thread-step;
// 4-slot circular buffer) implemented with the v5-PROVEN codegen pattern:
// persistent state = flat 1-D F4 arrays with literal indices only, role
// rotation by passing different POINTERS to a lambda (pure renaming, zero
// movs), 12-call unrolled rotation (lcm(4,3)), slots = absolute slab&3.
// Rings: center row cA..cD (depth 4: XP->C->XM->X2M), y+-1 rows pA..pC /
// qA..qC (depth 3: DPP->YP->DMP). Direct reads: X2P (x+2), Y2P/Y2M (x).

typedef float F4 __attribute__((ext_vector_type(4)));

#define DIM 160
#define SX (DIM * DIM * 3)          // 76800
#define SY (DIM * 3)                // 480
#define FSZ ((long long)DIM * SX)
#define TOT (4LL * FSZ)

#define ROWS 20                     // staged y rows per slab (16 out + 4 halo)
#define ROWU 37                     // 16B units per row (36 used + 1 pad)
#define USED_U (ROWS * ROWU)        // 740
#define SLICE_U 744                 // padded to mult of 8
#define SLICE_F (SLICE_U * 4)       // 2976 floats
#define SLOTS 4
#define STEPS 26
#define NSEG 6
#define NMS 4                       // m segments (128 output floats each)
#define NYT 10                      // y tiles (16 rows each)
#define NBLK (4 * NSEG * NMS * NYT) // 960
#define CPX (NBLK / 8)              // 120

#define CB(a, i) a[(i) >> 2][(i) & 3]

__global__ __launch_bounds__(256, 2) void be_kernel(const float* __restrict__ f,
                                                    float* __restrict__ out) {
    __shared__ float lds[SLICE_F * SLOTS];   // 47616 B
    const int tid = threadIdx.x;

    // bijective XCD chunking; same-XCD blocks share (b, xseg) slab volumes
    int lid = (blockIdx.x & 7) * CPX + (blockIdx.x >> 3);
    int p2i = lid / (NMS * NYT);
    int q2i = lid % (NMS * NYT);
    int b = p2i / NSEG, xseg = p2i % NSEG;
    int ms = q2i / NYT, yt = q2i % NYT;

    const int X0 = 2 + xseg * STEPS;
    const int gy0 = 16 * yt;                 // first staged global y row
    const int core = 4 + 128 * ms;           // first output m of this segment
    const int Gm = core - 8;                 // staged m start (16B-aligned)
    const long long bb = (long long)b * FSZ;
    const float* fbase = f + bb;
    const float* fend = f + (TOT - 4);

    const int t = tid >> 4;                  // m-tile 0..15
    const int yy = tid & 15;                 // y row within tile
    const int m0 = core + 8 * t;
    const int y = 2 + 16 * yt + yy;

    int jlo = 6 - m0; if (jlo < 0) jlo = 0;  // valid m in [6, 474)
    int jhi = 474 - m0; if (jhi > 8) jhi = 8;
    if (y >= DIM - 2) jhi = -1;              // y edge mask

    // unit of (center row, m0-8); every LDS access is slot-base + rc + imm
    const int rc = (yy + 2) * ROWU + 2 * t;

    // stage chunk global offsets (fixed per thread)
    long long choff[3];
#pragma unroll
    for (int it = 0; it < 3; ++it) {
        int c = it * 256 + tid;
        int row = c / ROWU, col = c - row * ROWU;
        choff[it] = (long long)(gy0 + row) * SY + Gm + 4 * col;
    }
    const bool ch2ok = (512 + tid) < USED_U;

    auto stage = [&](int slab) {
        int slot = slab & 3;                 // absolute slot mapping
        long long sb = (long long)slab * SX;
#pragma unroll
        for (int it = 0; it < 3; ++it) {
            if (it < 2 || ch2ok) {
                const float* gp = fbase + (sb + choff[it]);
                gp = gp < f ? f : gp;        // clamp buffer ends (masked data)
                gp = gp > fend ? fend : gp;
                __builtin_amdgcn_global_load_lds(
                    (const __attribute__((address_space(1))) unsigned int*)gp,
                    (__attribute__((address_space(3))) unsigned int*)
                        ((__attribute__((address_space(3))) float*)lds
                         + slot * SLICE_F + 4 * (it * 256 + tid)),
                    16, 0, 0);
            }
        }
    };

    auto LD = [&](const float* base, int unit) -> F4 {
        return *reinterpret_cast<const F4*>(base + 4 * unit);
    };

    // prologue: slabs X0-2..X0+1
    stage(X0 - 2); stage(X0 - 1); stage(X0); stage(X0 + 1);
    __syncthreads();

    // persistent ring state (1-D arrays, literal indices only — v5 pattern)
    F4 cA[6], cB[6], cC[6], cD[6];
    F4 pA[4], pB[4], pC[4], qA[4], qB[4], qC[4];
    {
        const float* L0  = lds + ((X0) & 3) * SLICE_F;       // slab X0
        const float* Lm1 = lds + ((X0 - 1) & 3) * SLICE_F;   // slab X0-1
        const float* Lm2 = lds + ((X0 - 2) & 3) * SLICE_F;   // slab X0-2
#pragma unroll
        for (int i = 0; i < 6; ++i) cD[i] = LD(L0, rc + i);          // C @ s0
#pragma unroll
        for (int i = 1; i < 5; ++i) cC[i] = LD(Lm1, rc + i);         // XM @ s0
        cB[2] = LD(Lm2, rc + 2); cB[3] = LD(Lm2, rc + 3);            // X2M @ s0
#pragma unroll
        for (int i = 0; i < 4; ++i) {
            pC[i] = LD(L0, rc + ROWU + 1 + i);                       // YP @ s0
            qC[i] = LD(L0, rc - ROWU + 1 + i);
        }
        pB[1] = LD(Lm1, rc + ROWU + 2); pB[2] = LD(Lm1, rc + ROWU + 3);  // DMP
        qB[1] = LD(Lm1, rc - ROWU + 2); qB[2] = LD(Lm1, rc - ROWU + 3);
    }
    __syncthreads();                 // seeds done before slot reuse
    stage(X0 + 2);                   // slot (X0+2)&3 == (X0-2)&3 (consumed)
    __syncthreads();                 // landed before step 0 reads it

    float e = 0.0f;                  // raw energy (x16 scale)

    // one x-step; roles via pointer args (c0=fresh/XP, c1=C, c2=XM, c3=X2M;
    // p0=fresh/DPP, p1=YP, p2=DMP; q mirror)
    auto step = [&](int x, bool do_stage,
                    F4* c0, F4* c1, F4* c2, F4* c3,
                    F4* p0, F4* p1, F4* p2,
                    F4* q0, F4* q1, F4* q2) {
        if (do_stage) stage(x + 3);          // over slab x-1 slot (reg-held)

        const float* Lx  = lds + ((x) & 3) * SLICE_F;       // slab x
        const float* Lx1 = lds + ((x + 1) & 3) * SLICE_F;   // slab x+1
        const float* Lx2 = lds + ((x + 2) & 3) * SLICE_F;   // slab x+2

        // fresh reads: 14 units from slab x+1
#pragma unroll
        for (int i = 0; i < 6; ++i) c0[i] = LD(Lx1, rc + i);
#pragma unroll
        for (int i = 0; i < 4; ++i) {
            p0[i] = LD(Lx1, rc + ROWU + 1 + i);
            q0[i] = LD(Lx1, rc - ROWU + 1 + i);
        }
        // direct reads: 6 units
        F4 X2Pa[2], Y2Pa[2], Y2Ma[2];
        X2Pa[0] = LD(Lx2, rc + 2);            X2Pa[1] = LD(Lx2, rc + 3);
        Y2Pa[0] = LD(Lx, rc + 2 * ROWU + 2);  Y2Pa[1] = LD(Lx, rc + 2 * ROWU + 3);
        Y2Ma[0] = LD(Lx, rc - 2 * ROWU + 2);  Y2Ma[1] = LD(Lx, rc - 2 * ROWU + 3);

        // float maps: center rows idx k = m-(m0-8); p/q rows idx i = m-(m0-4)
#pragma unroll
        for (int j = 0; j < 8; ++j) {
            float ctr2 = 2.0f * CB(c1, j + 8);
            float dxx = (CB(X2Pa, j) + CB(c3, j + 8)) - ctr2;
            float dyy = (CB(Y2Pa, j) + CB(Y2Ma, j)) - ctr2;
            float dzz = (CB(c1, j + 2) + CB(c1, j + 14)) - ctr2;
            float dxy = (CB(p0, j + 4) - CB(p2, j + 4))
                      - (CB(q0, j + 4) - CB(q2, j + 4));
            float dxz = (CB(c0, j + 11) - CB(c2, j + 11))
                      - (CB(c0, j + 5) - CB(c2, j + 5));
            float dyz = (CB(p1, j + 7) - CB(q1, j + 7))
                      - (CB(p1, j + 1) - CB(q1, j + 1));
            float dd = dxx * dxx + dyy * dyy + dzz * dzz;
            float dc = dxy * dxy + dxz * dxz + dyz * dyz;
            float msk = (j >= jlo && j < jhi) ? 1.0f : 0.0f;
            e += msk * (dd + 2.0f * dc);
        }

        __syncthreads();   // drains stage vmcnt + orders slot reuse
    };

    // rotation: fresh c = [A,B,C,D][s&3]; c1=(s+3)&3, c2=(s+2)&3, c3=(s+1)&3
    //           fresh p = [A,B,C][s%3]; p1=(s+2)%3, p2=(s+1)%3   (q mirror)
    for (int it2 = 0; it2 < 2; ++it2) {
        int xb = X0 + it2 * 12;
        step(xb + 0,  true, cA, cD, cC, cB, pA, pC, pB, qA, qC, qB);
        step(xb + 1,  true, cB, cA, cD, cC, pB, pA, pC, qB, qA, qC);
        step(xb + 2,  true, cC, cB, cA, cD, pC, pB, pA, qC, qB, qA);
        step(xb + 3,  true, cD, cC, cB, cA, pA, pC, pB, qA, qC, qB);
        step(xb + 4,  true, cA, cD, cC, cB, pB, pA, pC, qB, qA, qC);
        step(xb + 5,  true, cB, cA, cD, cC, pC, pB, pA, qC, qB, qA);
        step(xb + 6,  true, cC, cB, cA, cD, pA, pC, pB, qA, qC, qB);
        step(xb + 7,  true, cD, cC, cB, cA, pB, pA, pC, qB, qA, qC);
        step(xb + 8,  true, cA, cD, cC, cB, pC, pB, pA, qC, qB, qA);
        step(xb + 9,  true, cB, cA, cD, cC, pA, pC, pB, qA, qC, qB);
        step(xb + 10, true, cC, cB, cA, cD, pB, pA, pC, qB, qA, qC);
        step(xb + 11, true, cD, cC, cB, cA, pC, pB, pA, qC, qB, qA);
    }
    step(X0 + 24, true,  cA, cD, cC, cB, pA, pC, pB, qA, qC, qB);
    step(X0 + 25, false, cB, cA, cD, cC, pB, pA, pC, qB, qA, qC);

    // wave reduce -> block reduce -> one atomic per block
#pragma unroll
    for (int off = 32; off > 0; off >>= 1) e += __shfl_down(e, off, 64);

    __shared__ float ws[4];
    int lane = tid & 63;
    int wid = tid >> 6;
    if (lane == 0) ws[wid] = e;
    __syncthreads();
    if (tid == 0) {
        // 0.0625 = (0.25)^2 from the two central-difference factors
        const float inv_count = 0.0625f / (156.0f * 156.0f * 156.0f * 3.0f);
        atomicAdd(&out[b], (ws[0] + ws[1] + ws[2] + ws[3]) * inv_count);
    }
}

extern "C" void kernel_launch(void* const* d_in, const int* in_sizes, int n_in,
                              void* d_out, int out_size, void* d_ws, size_t ws_size,
                              hipStream_t stream) {
    const float* f = (const float*)d_in[0];
    float* out = (float*)d_out;

    hipMemsetAsync(d_out, 0, out_size * sizeof(float), stream);

    be_kernel<<<dim3(NBLK), dim3(256), 0, stream>>>(f, out);
}

// Round 14
// 165.335 us; speedup vs baseline: 6.5715x; 6.5715x over previous
//
#include <hip/hip_runtime.h>

// BendingEnergy: fused 19-point stencil + per-batch mean, LDS x-march v10.
// 20-units/thread-step dataflow (each LDS row read ONCE per x-march) with
// scratch-proof codegen: persistent ring = nine kernel-scope arrays, step
// body is a TOKEN-PASTING MACRO naming them directly (no pointers, no
// references, no calls -> no alias analysis involved; failures v6/v8/v9 all
// routed state through mutable pointers). Ring depth 3 (fresh@x+1 serves
// XP -> C -> XM) + copy-out of units 2,3 before overwrite supplies X2M
// (slab x-2) for free. Direct reads: X2P (x+2), Y2P/Y2M (x).

typedef float F4 __attribute__((ext_vector_type(4)));

#define DIM 160
#define SX (DIM * DIM * 3)          // 76800
#define SY (DIM * 3)                // 480
#define FSZ ((long long)DIM * SX)
#define TOT (4LL * FSZ)

#define ROWS 20                     // staged y rows per slab (16 out + 4 halo)
#define ROWU 37                     // 16B units per row (36 used + 1 pad)
#define USED_U (ROWS * ROWU)        // 740
#define SLICE_U 744                 // padded to mult of 8
#define SLICE_F (SLICE_U * 4)       // 2976 floats
#define SLOTS 4
#define STEPS 26
#define NSEG 6
#define NMS 4                       // m segments (128 output floats each)
#define NYT 10                      // y tiles (16 rows each)
#define NBLK (4 * NSEG * NMS * NYT) // 960
#define CPX (NBLK / 8)              // 120

#define CB(a, i) a[(i) >> 2][(i) & 3]

// One x-step. F/M/O are ring-set name tokens: F = fresh (slab x+1: XP role),
// M = read last step (slab x: C/YP role), O = read 2 steps ago (slab x-1:
// XM/DMP role). F's old contents (slab x-2) supply X2M via copy-out.
#define STEP(x_, DOSTAGE, F, M, O)                                          \
  {                                                                         \
    F4 x2m0 = c##F[2], x2m1 = c##F[3];          /* slab x-2, pre-overwrite */\
    if (DOSTAGE) stage(x_ + 3);                                             \
    const float* Lx  = lds + ((x_) & 3) * SLICE_F;                          \
    const float* Lx1 = lds + (((x_) + 1) & 3) * SLICE_F;                    \
    const float* Lx2 = lds + (((x_) + 2) & 3) * SLICE_F;                    \
    _Pragma("unroll")                                                       \
    for (int i = 0; i < 6; ++i) c##F[i] = LD(Lx1, rc + i);                  \
    _Pragma("unroll")                                                       \
    for (int i = 0; i < 4; ++i) {                                           \
      p##F[i] = LD(Lx1, rc + ROWU + 1 + i);                                 \
      q##F[i] = LD(Lx1, rc - ROWU + 1 + i);                                 \
    }                                                                       \
    F4 X2Pa[2], X2Ma[2], Y2Pa[2], Y2Ma[2];                                  \
    X2Pa[0] = LD(Lx2, rc + 2);           X2Pa[1] = LD(Lx2, rc + 3);         \
    Y2Pa[0] = LD(Lx, rc + 2 * ROWU + 2); Y2Pa[1] = LD(Lx, rc + 2 * ROWU + 3);\
    Y2Ma[0] = LD(Lx, rc - 2 * ROWU + 2); Y2Ma[1] = LD(Lx, rc - 2 * ROWU + 3);\
    X2Ma[0] = x2m0; X2Ma[1] = x2m1;                                         \
    _Pragma("unroll")                                                       \
    for (int j = 0; j < 8; ++j) {                                           \
      float ctr2 = 2.0f * CB(c##M, j + 8);                                  \
      float dxx = (CB(X2Pa, j) + CB(X2Ma, j)) - ctr2;                       \
      float dyy = (CB(Y2Pa, j) + CB(Y2Ma, j)) - ctr2;                       \
      float dzz = (CB(c##M, j + 2) + CB(c##M, j + 14)) - ctr2;              \
      float dxy = (CB(p##F, j + 4) - CB(p##O, j + 4))                       \
                - (CB(q##F, j + 4) - CB(q##O, j + 4));                      \
      float dxz = (CB(c##F, j + 11) - CB(c##O, j + 11))                     \
                - (CB(c##F, j + 5) - CB(c##O, j + 5));                      \
      float dyz = (CB(p##M, j + 7) - CB(q##M, j + 7))                       \
                - (CB(p##M, j + 1) - CB(q##M, j + 1));                      \
      float dd = dxx * dxx + dyy * dyy + dzz * dzz;                         \
      float dc = dxy * dxy + dxz * dxz + dyz * dyz;                         \
      float msk = (j >= jlo && j < jhi) ? 1.0f : 0.0f;                      \
      e += msk * (dd + 2.0f * dc);                                          \
    }                                                                       \
    __syncthreads();                                                        \
  }

__global__ __launch_bounds__(256, 2) void be_kernel(const float* __restrict__ f,
                                                    float* __restrict__ out) {
    __shared__ float lds[SLICE_F * SLOTS];   // 47616 B
    const int tid = threadIdx.x;

    // bijective XCD chunking; same-XCD blocks share (b, xseg) slab volumes
    int lid = (blockIdx.x & 7) * CPX + (blockIdx.x >> 3);
    int p2i = lid / (NMS * NYT);
    int q2i = lid % (NMS * NYT);
    int b = p2i / NSEG, xseg = p2i % NSEG;
    int ms = q2i / NYT, yt = q2i % NYT;

    const int X0 = 2 + xseg * STEPS;
    const int gy0 = 16 * yt;                 // first staged global y row
    const int core = 4 + 128 * ms;           // first output m of this segment
    const int Gm = core - 8;                 // staged m start (16B-aligned)
    const long long bb = (long long)b * FSZ;
    const float* fbase = f + bb;
    const float* fend = f + (TOT - 4);

    const int t = tid >> 4;                  // m-tile 0..15
    const int yy = tid & 15;                 // y row within tile
    const int m0 = core + 8 * t;
    const int y = 2 + 16 * yt + yy;

    int jlo = 6 - m0; if (jlo < 0) jlo = 0;  // valid m in [6, 474)
    int jhi = 474 - m0; if (jhi > 8) jhi = 8;
    if (y >= DIM - 2) jhi = -1;              // y edge mask

    // unit of (center row, m0-8); every LDS access is slot-base + rc + imm
    const int rc = (yy + 2) * ROWU + 2 * t;

    // stage chunk global offsets (fixed per thread)
    long long choff[3];
#pragma unroll
    for (int it = 0; it < 3; ++it) {
        int c = it * 256 + tid;
        int row = c / ROWU, col = c - row * ROWU;
        choff[it] = (long long)(gy0 + row) * SY + Gm + 4 * col;
    }
    const bool ch2ok = (512 + tid) < USED_U;

    auto stage = [&](int slab) {
        int slot = slab & 3;                 // absolute slot mapping
        long long sb = (long long)slab * SX;
#pragma unroll
        for (int it = 0; it < 3; ++it) {
            if (it < 2 || ch2ok) {
                const float* gp = fbase + (sb + choff[it]);
                gp = gp < f ? f : gp;        // clamp buffer ends (masked data)
                gp = gp > fend ? fend : gp;
                __builtin_amdgcn_global_load_lds(
                    (const __attribute__((address_space(1))) unsigned int*)gp,
                    (__attribute__((address_space(3))) unsigned int*)
                        ((__attribute__((address_space(3))) float*)lds
                         + slot * SLICE_F + 4 * (it * 256 + tid)),
                    16, 0, 0);
            }
        }
    };

    auto LD = [&](const float* base, int unit) -> F4 {
        return *reinterpret_cast<const F4*>(base + 4 * unit);
    };

    // prologue: slabs X0-2..X0+1
    stage(X0 - 2); stage(X0 - 1); stage(X0); stage(X0 + 1);
    __syncthreads();

    // persistent ring state: kernel-scope arrays, literal indices only,
    // accessed ONLY by name via the STEP macro (no pointers/references).
    F4 cA[6], cB[6], cC[6];
    F4 pA[4], pB[4], pC[4], qA[4], qB[4], qC[4];
    {
        const float* Ls0  = lds + ((X0) & 3) * SLICE_F;      // slab X0
        const float* Lsm1 = lds + ((X0 - 1) & 3) * SLICE_F;  // slab X0-1
        const float* Lsm2 = lds + ((X0 - 2) & 3) * SLICE_F;  // slab X0-2
#pragma unroll
        for (int i = 0; i < 6; ++i) {
            cC[i] = LD(Ls0, rc + i);         // "read at s=-1" (C role @ s0)
            cB[i] = LD(Lsm1, rc + i);        // "read at s=-2" (XM role @ s0)
            cA[i] = LD(Lsm2, rc + i);        // units 2,3 -> X2M @ s0
        }
#pragma unroll
        for (int i = 0; i < 4; ++i) {
            pC[i] = LD(Ls0, rc + ROWU + 1 + i);
            qC[i] = LD(Ls0, rc - ROWU + 1 + i);
            pB[i] = LD(Lsm1, rc + ROWU + 1 + i);
            qB[i] = LD(Lsm1, rc - ROWU + 1 + i);
            pA[i] = pB[i]; qA[i] = qB[i];    // dummy init (overwritten @ s0)
        }
    }
    __syncthreads();                 // seeds done before slot reuse
    stage(X0 + 2);                   // slot (X0+2)&3 == (X0-2)&3 (consumed)
    __syncthreads();                 // landed before step 0 reads it

    float e = 0.0f;                  // raw energy (x16 scale)

    // rotation: s%3 = 0 -> (F,M,O)=(A,C,B); 1 -> (B,A,C); 2 -> (C,B,A)
    for (int it2 = 0; it2 < 8; ++it2) {
        int xb = X0 + 3 * it2;
        STEP(xb,     true, A, C, B)
        STEP(xb + 1, true, B, A, C)
        STEP(xb + 2, true, C, B, A)
    }
    STEP(X0 + 24, true,  A, C, B)
    STEP(X0 + 25, false, B, A, C)

    // wave reduce -> block reduce -> one atomic per block
#pragma unroll
    for (int off = 32; off > 0; off >>= 1) e += __shfl_down(e, off, 64);

    __shared__ float ws[4];
    int lane = tid & 63;
    int wid = tid >> 6;
    if (lane == 0) ws[wid] = e;
    __syncthreads();
    if (tid == 0) {
        // 0.0625 = (0.25)^2 from the two central-difference factors
        const float inv_count = 0.0625f / (156.0f * 156.0f * 156.0f * 3.0f);
        atomicAdd(&out[b], (ws[0] + ws[1] + ws[2] + ws[3]) * inv_count);
    }
}

extern "C" void kernel_launch(void* const* d_in, const int* in_sizes, int n_in,
                              void* d_out, int out_size, void* d_ws, size_t ws_size,
                              hipStream_t stream) {
    const float* f = (const float*)d_in[0];
    float* out = (float*)d_out;

    hipMemsetAsync(d_out, 0, out_size * sizeof(float), stream);

    be_kernel<<<dim3(NBLK), dim3(256), 0, stream>>>(f, out);
}

// Round 15
// 163.199 us; speedup vs baseline: 6.6575x; 1.0131x over previous
//
#include <hip/hip_runtime.h>

// BendingEnergy: fused 19-point stencil + per-batch mean, LDS x-march v11.
// = v10 (20 units/thread-step; token-macro rings, depth 3 + copy-out for
// X2M; 4-slot circular buffer, 47.6 KB) + amdgpu_waves_per_eu(2,2): pins the
// register allocator's occupancy target to our LDS-bound occupancy (2
// blocks/CU = 2 waves/EU) -> 256-VGPR budget. Round 14 showed the allocator
// targeting 128 VGPRs (4 waves/EU, ignoring LDS) and spilling ~40 regs
// (WRITE_SIZE 67 MB); the state needs ~170-200 regs.

typedef float F4 __attribute__((ext_vector_type(4)));

#define DIM 160
#define SX (DIM * DIM * 3)          // 76800
#define SY (DIM * 3)                // 480
#define FSZ ((long long)DIM * SX)
#define TOT (4LL * FSZ)

#define ROWS 20                     // staged y rows per slab (16 out + 4 halo)
#define ROWU 37                     // 16B units per row (36 used + 1 pad)
#define USED_U (ROWS * ROWU)        // 740
#define SLICE_U 744                 // padded to mult of 8
#define SLICE_F (SLICE_U * 4)       // 2976 floats
#define SLOTS 4
#define STEPS 26
#define NSEG 6
#define NMS 4                       // m segments (128 output floats each)
#define NYT 10                      // y tiles (16 rows each)
#define NBLK (4 * NSEG * NMS * NYT) // 960
#define CPX (NBLK / 8)              // 120

#define CB(a, i) a[(i) >> 2][(i) & 3]

// One x-step. F/M/O are ring-set name tokens: F = fresh (slab x+1: XP role),
// M = read last step (slab x: C/YP role), O = read 2 steps ago (slab x-1:
// XM/DMP role). F's old contents (slab x-2) supply X2M via copy-out.
#define STEP(x_, DOSTAGE, F, M, O)                                          \
  {                                                                         \
    F4 x2m0 = c##F[2], x2m1 = c##F[3];          /* slab x-2, pre-overwrite */\
    if (DOSTAGE) stage(x_ + 3);                                             \
    const float* Lx  = lds + ((x_) & 3) * SLICE_F;                          \
    const float* Lx1 = lds + (((x_) + 1) & 3) * SLICE_F;                    \
    const float* Lx2 = lds + (((x_) + 2) & 3) * SLICE_F;                    \
    _Pragma("unroll")                                                       \
    for (int i = 0; i < 6; ++i) c##F[i] = LD(Lx1, rc + i);                  \
    _Pragma("unroll")                                                       \
    for (int i = 0; i < 4; ++i) {                                           \
      p##F[i] = LD(Lx1, rc + ROWU + 1 + i);                                 \
      q##F[i] = LD(Lx1, rc - ROWU + 1 + i);                                 \
    }                                                                       \
    F4 X2Pa[2], X2Ma[2], Y2Pa[2], Y2Ma[2];                                  \
    X2Pa[0] = LD(Lx2, rc + 2);           X2Pa[1] = LD(Lx2, rc + 3);         \
    Y2Pa[0] = LD(Lx, rc + 2 * ROWU + 2); Y2Pa[1] = LD(Lx, rc + 2 * ROWU + 3);\
    Y2Ma[0] = LD(Lx, rc - 2 * ROWU + 2); Y2Ma[1] = LD(Lx, rc - 2 * ROWU + 3);\
    X2Ma[0] = x2m0; X2Ma[1] = x2m1;                                         \
    _Pragma("unroll")                                                       \
    for (int j = 0; j < 8; ++j) {                                           \
      float ctr2 = 2.0f * CB(c##M, j + 8);                                  \
      float dxx = (CB(X2Pa, j) + CB(X2Ma, j)) - ctr2;                       \
      float dyy = (CB(Y2Pa, j) + CB(Y2Ma, j)) - ctr2;                       \
      float dzz = (CB(c##M, j + 2) + CB(c##M, j + 14)) - ctr2;              \
      float dxy = (CB(p##F, j + 4) - CB(p##O, j + 4))                       \
                - (CB(q##F, j + 4) - CB(q##O, j + 4));                      \
      float dxz = (CB(c##F, j + 11) - CB(c##O, j + 11))                     \
                - (CB(c##F, j + 5) - CB(c##O, j + 5));                      \
      float dyz = (CB(p##M, j + 7) - CB(q##M, j + 7))                       \
                - (CB(p##M, j + 1) - CB(q##M, j + 1));                      \
      float dd = dxx * dxx + dyy * dyy + dzz * dzz;                         \
      float dc = dxy * dxy + dxz * dxz + dyz * dyz;                         \
      float msk = (j >= jlo && j < jhi) ? 1.0f : 0.0f;                      \
      e += msk * (dd + 2.0f * dc);                                          \
    }                                                                       \
    __syncthreads();                                                        \
  }

__global__ __launch_bounds__(256)
__attribute__((amdgpu_waves_per_eu(2, 2)))
void be_kernel(const float* __restrict__ f, float* __restrict__ out) {
    __shared__ float lds[SLICE_F * SLOTS];   // 47616 B
    const int tid = threadIdx.x;

    // bijective XCD chunking; same-XCD blocks share (b, xseg) slab volumes
    int lid = (blockIdx.x & 7) * CPX + (blockIdx.x >> 3);
    int p2i = lid / (NMS * NYT);
    int q2i = lid % (NMS * NYT);
    int b = p2i / NSEG, xseg = p2i % NSEG;
    int ms = q2i / NYT, yt = q2i % NYT;

    const int X0 = 2 + xseg * STEPS;
    const int gy0 = 16 * yt;                 // first staged global y row
    const int core = 4 + 128 * ms;           // first output m of this segment
    const int Gm = core - 8;                 // staged m start (16B-aligned)
    const long long bb = (long long)b * FSZ;
    const float* fbase = f + bb;
    const float* fend = f + (TOT - 4);

    const int t = tid >> 4;                  // m-tile 0..15
    const int yy = tid & 15;                 // y row within tile
    const int m0 = core + 8 * t;
    const int y = 2 + 16 * yt + yy;

    int jlo = 6 - m0; if (jlo < 0) jlo = 0;  // valid m in [6, 474)
    int jhi = 474 - m0; if (jhi > 8) jhi = 8;
    if (y >= DIM - 2) jhi = -1;              // y edge mask

    // unit of (center row, m0-8); every LDS access is slot-base + rc + imm
    const int rc = (yy + 2) * ROWU + 2 * t;

    // stage chunk global offsets (fixed per thread)
    long long choff[3];
#pragma unroll
    for (int it = 0; it < 3; ++it) {
        int c = it * 256 + tid;
        int row = c / ROWU, col = c - row * ROWU;
        choff[it] = (long long)(gy0 + row) * SY + Gm + 4 * col;
    }
    const bool ch2ok = (512 + tid) < USED_U;

    auto stage = [&](int slab) {
        int slot = slab & 3;                 // absolute slot mapping
        long long sb = (long long)slab * SX;
#pragma unroll
        for (int it = 0; it < 3; ++it) {
            if (it < 2 || ch2ok) {
                const float* gp = fbase + (sb + choff[it]);
                gp = gp < f ? f : gp;        // clamp buffer ends (masked data)
                gp = gp > fend ? fend : gp;
                __builtin_amdgcn_global_load_lds(
                    (const __attribute__((address_space(1))) unsigned int*)gp,
                    (__attribute__((address_space(3))) unsigned int*)
                        ((__attribute__((address_space(3))) float*)lds
                         + slot * SLICE_F + 4 * (it * 256 + tid)),
                    16, 0, 0);
            }
        }
    };

    auto LD = [&](const float* base, int unit) -> F4 {
        return *reinterpret_cast<const F4*>(base + 4 * unit);
    };

    // prologue: slabs X0-2..X0+1
    stage(X0 - 2); stage(X0 - 1); stage(X0); stage(X0 + 1);
    __syncthreads();

    // persistent ring state: kernel-scope arrays, literal indices only,
    // accessed ONLY by name via the STEP macro (no pointers/references).
    F4 cA[6], cB[6], cC[6];
    F4 pA[4], pB[4], pC[4], qA[4], qB[4], qC[4];
    {
        const float* Ls0  = lds + ((X0) & 3) * SLICE_F;      // slab X0
        const float* Lsm1 = lds + ((X0 - 1) & 3) * SLICE_F;  // slab X0-1
        const float* Lsm2 = lds + ((X0 - 2) & 3) * SLICE_F;  // slab X0-2
#pragma unroll
        for (int i = 0; i < 6; ++i) {
            cC[i] = LD(Ls0, rc + i);         // "read at s=-1" (C role @ s0)
            cB[i] = LD(Lsm1, rc + i);        // "read at s=-2" (XM role @ s0)
            cA[i] = LD(Lsm2, rc + i);        // units 2,3 -> X2M @ s0
        }
#pragma unroll
        for (int i = 0; i < 4; ++i) {
            pC[i] = LD(Ls0, rc + ROWU + 1 + i);
            qC[i] = LD(Ls0, rc - ROWU + 1 + i);
            pB[i] = LD(Lsm1, rc + ROWU + 1 + i);
            qB[i] = LD(Lsm1, rc - ROWU + 1 + i);
            pA[i] = pB[i]; qA[i] = qB[i];    // dummy init (overwritten @ s0)
        }
    }
    __syncthreads();                 // seeds done before slot reuse
    stage(X0 + 2);                   // slot (X0+2)&3 == (X0-2)&3 (consumed)
    __syncthreads();                 // landed before step 0 reads it

    float e = 0.0f;                  // raw energy (x16 scale)

    // rotation: s%3 = 0 -> (F,M,O)=(A,C,B); 1 -> (B,A,C); 2 -> (C,B,A)
    for (int it2 = 0; it2 < 8; ++it2) {
        int xb = X0 + 3 * it2;
        STEP(xb,     true, A, C, B)
        STEP(xb + 1, true, B, A, C)
        STEP(xb + 2, true, C, B, A)
    }
    STEP(X0 + 24, true,  A, C, B)
    STEP(X0 + 25, false, B, A, C)

    // wave reduce -> block reduce -> one atomic per block
#pragma unroll
    for (int off = 32; off > 0; off >>= 1) e += __shfl_down(e, off, 64);

    __shared__ float ws[4];
    int lane = tid & 63;
    int wid = tid >> 6;
    if (lane == 0) ws[wid] = e;
    __syncthreads();
    if (tid == 0) {
        // 0.0625 = (0.25)^2 from the two central-difference factors
        const float inv_count = 0.0625f / (156.0f * 156.0f * 156.0f * 3.0f);
        atomicAdd(&out[b], (ws[0] + ws[1] + ws[2] + ws[3]) * inv_count);
    }
}

extern "C" void kernel_launch(void* const* d_in, const int* in_sizes, int n_in,
                              void* d_out, int out_size, void* d_ws, size_t ws_size,
                              hipStream_t stream) {
    const float* f = (const float*)d_in[0];
    float* out = (float*)d_out;

    hipMemsetAsync(d_out, 0, out_size * sizeof(float), stream);

    be_kernel<<<dim3(NBLK), dim3(256), 0, stream>>>(f, out);
}

// Round 16
// 150.145 us; speedup vs baseline: 7.2363x; 1.0869x over previous
//
#include <hip/hip_runtime.h>

// BendingEnergy: fused 19-point stencil + per-batch mean, LDS x-march v12.
// = v5 (87us proven: ping-pong reg FIFOs for XM/DPP/DMP, VGPR 112, no spill)
// + two low-register upgrades:
//  1) X2M from regs: the XM FIFO set (slab x-1) is copied (2 units) into
//     x2m[] before overwrite, consumed next step -> slab x-2 never read from
//     LDS; 30 -> 28 units/thread-step.
//  2) 4 slots (only slabs x..x+3 live) -> LDS 47.6 KB -> 3 blocks/CU
//     (12 waves/CU, +50% TLP to hide barrier drain). NSEG=13 x STEPS=12
//     (2080 blocks) keeps the 768-block-capacity machine ~90% packed and
//     makes X0 === 2 (mod 4) so slot indices are cheap.
// Register envelope kept at ~120 (<128 allocator cliff, rounds 10-15 lesson).

typedef float F4 __attribute__((ext_vector_type(4)));

#define DIM 160
#define SX (DIM * DIM * 3)          // 76800
#define SY (DIM * 3)                // 480
#define FSZ ((long long)DIM * SX)
#define TOT (4LL * FSZ)

#define ROWS 20                     // staged y rows per slab (16 out + 4 halo)
#define ROWU 37                     // 16B units per row (36 used + 1 pad), ODD
#define USED_U (ROWS * ROWU)        // 740
#define SLICE_U 744                 // padded to mult of 8
#define SLICE_F (SLICE_U * 4)       // 2976 floats
#define SLOTS 4
#define STEPS 12
#define NSEG 13                     // 13 * 12 = 156
#define NMS 4                       // m segments (128 output floats each)
#define NYT 10                      // y tiles (16 rows each)
#define NBLK (4 * NSEG * NMS * NYT) // 2080
#define CPX (NBLK / 8)              // 260

#define CB(a, i) a[(i) >> 2][(i) & 3]

__global__ __launch_bounds__(256, 3) void be_kernel(const float* __restrict__ f,
                                                    float* __restrict__ out) {
    __shared__ float lds[SLICE_F * SLOTS];   // 47616 B -> 3 blocks/CU
    const int tid = threadIdx.x;

    // bijective XCD chunking; same-XCD blocks share (b, xseg) slab volumes
    int lid = (blockIdx.x & 7) * CPX + (blockIdx.x >> 3);
    int p2i = lid / (NMS * NYT);
    int q2i = lid % (NMS * NYT);
    int b = p2i / NSEG, xseg = p2i % NSEG;
    int ms = q2i / NYT, yt = q2i % NYT;

    const int X0 = 2 + xseg * STEPS;         // X0 % 4 == 2 always
    const int gy0 = 16 * yt;                 // first staged global y row
    const int core = 4 + 128 * ms;           // first output m of this segment
    const int Gm = core - 8;                 // staged m start (16B-aligned)
    const long long bb = (long long)b * FSZ;
    const float* fbase = f + bb;
    const float* fend = f + (TOT - 4);

    // lane remap (v5-proven): yy bit0 = tid bit3 -> bank-residue spread
    const int t = tid >> 4;                  // m-tile 0..15
    const int yy = ((tid >> 3) & 1) | ((tid & 7) << 1);  // y row 0..15
    const int m0 = core + 8 * t;
    const int y = 2 + 16 * yt + yy;

    int jlo = 6 - m0; if (jlo < 0) jlo = 0;  // valid m in [6, 474)
    int jhi = 474 - m0; if (jhi > 8) jhi = 8;
    if (y >= DIM - 2) jhi = -1;              // y edge mask

    // unit of (center row, m0-8); every LDS access is slot-base + rc + imm
    const int rc = (yy + 2) * ROWU + 2 * t;

    // stage chunk global offsets (fixed per thread)
    long long choff[3];
#pragma unroll
    for (int it = 0; it < 3; ++it) {
        int c = it * 256 + tid;
        int row = c / ROWU, col = c - row * ROWU;
        choff[it] = (long long)(gy0 + row) * SY + Gm + 4 * col;
    }
    const bool ch2ok = (512 + tid) < USED_U;

    auto stage = [&](int slab, int slot) {
        long long sb = (long long)slab * SX;
#pragma unroll
        for (int it = 0; it < 3; ++it) {
            if (it < 2 || ch2ok) {
                const float* gp = fbase + (sb + choff[it]);
                gp = gp < f ? f : gp;        // clamp buffer ends (masked data)
                gp = gp > fend ? fend : gp;
                __builtin_amdgcn_global_load_lds(
                    (const __attribute__((address_space(1))) unsigned int*)gp,
                    (__attribute__((address_space(3))) unsigned int*)
                        ((__attribute__((address_space(3))) float*)lds
                         + slot * SLICE_F + 4 * (it * 256 + tid)),
                    16, 0, 0);
            }
        }
    };

    // prologue: slabs X0-2..X0+1 -> slots 0..3 (X0 % 4 == 2)
    stage(X0 - 2, 0); stage(X0 - 1, 1); stage(X0, 2); stage(X0 + 1, 3);
    __syncthreads();

    // FIFO seeds (v5 pattern): set a consumed at even steps, b at odd.
    // fa_xm/fb_xm: units rc+1..4 (floats m0-4..m0+11) of slabs X0-1 / X0.
    // fa_pp/pm, fb_pp/pm: units rc+-ROWU+2..3 (floats m0..m0+7).
    // x2m: units rc+2..3 of slab X0-2 (X2M for step 0).
    F4 fa_xm[4], fa_pp[2], fa_pm[2], fb_xm[4], fb_pp[2], fb_pm[2], x2m[2];
    {
        const float* S1 = lds + 1 * SLICE_F;     // slab X0-1
        const float* S2 = lds + 2 * SLICE_F;     // slab X0
        const float* S0 = lds + 0 * SLICE_F;     // slab X0-2
#pragma unroll
        for (int i = 0; i < 4; ++i) {
            fa_xm[i] = *(const F4*)(S1 + 4 * (rc + 1 + i));
            fb_xm[i] = *(const F4*)(S2 + 4 * (rc + 1 + i));
        }
#pragma unroll
        for (int i = 0; i < 2; ++i) {
            fa_pp[i] = *(const F4*)(S1 + 4 * (rc + ROWU + 2 + i));
            fa_pm[i] = *(const F4*)(S1 + 4 * (rc - ROWU + 2 + i));
            fb_pp[i] = *(const F4*)(S2 + 4 * (rc + ROWU + 2 + i));
            fb_pm[i] = *(const F4*)(S2 + 4 * (rc - ROWU + 2 + i));
        }
        x2m[0] = *(const F4*)(S0 + 4 * (rc + 2));
        x2m[1] = *(const F4*)(S0 + 4 * (rc + 3));
    }
    __syncthreads();                 // seeds done before slot 0 reuse
    stage(X0 + 2, 0);                // slab X0+2 -> slot 0 (over X0-2)
    __syncthreads();                 // landed before step 0 reads it

    float e = 0.0f;                  // raw energy (x16 scale)

    // one x-step at s (x = X0+s); Fxm/Fpp/Fpm = this step's x-1 FIFO set
    // (overwritten with x+1 data); x2m = slab x-2 middles, updated from Fxm.
    auto step = [&](int s, bool do_stage, F4* Fxm, F4* Fpp, F4* Fpm) {
        F4 sv0 = Fxm[1], sv1 = Fxm[2];       // slab x-1 -> X2M of step s+1
        if (do_stage) stage(X0 + s + 3, (s + 1) & 3);

        const float* Lx  = lds + ((s + 2) & 3) * SLICE_F;  // slab x
        const float* Lx1 = lds + ((s + 3) & 3) * SLICE_F;  // slab x+1
        const float* Lx2 = lds + ((s) & 3) * SLICE_F;      // slab x+2

        float C[24];
        F4 XPn[4], PPn[2], PMn[2], YP4[4], YM4[4], X2Pa[2], Y2Pa[2], Y2Ma[2];
        // C: units rc..rc+5 (floats m0-8..m0+15), slab x
#pragma unroll
        for (int i = 0; i < 6; ++i)
            *(F4*)(&C[4 * i]) = *(const F4*)(Lx + 4 * (rc + i));
        // fresh x+1 row (floats m0-4..m0+11) + diagonals (floats m0..m0+7)
#pragma unroll
        for (int i = 0; i < 4; ++i) {
            XPn[i] = *(const F4*)(Lx1 + 4 * (rc + 1 + i));
            YP4[i] = *(const F4*)(Lx + 4 * (rc + ROWU + 1 + i));
            YM4[i] = *(const F4*)(Lx + 4 * (rc - ROWU + 1 + i));
        }
#pragma unroll
        for (int i = 0; i < 2; ++i) {
            PPn[i]  = *(const F4*)(Lx1 + 4 * (rc + ROWU + 2 + i));
            PMn[i]  = *(const F4*)(Lx1 + 4 * (rc - ROWU + 2 + i));
            X2Pa[i] = *(const F4*)(Lx2 + 4 * (rc + 2 + i));
            Y2Pa[i] = *(const F4*)(Lx + 4 * (rc + 2 * ROWU + 2 + i));
            Y2Ma[i] = *(const F4*)(Lx + 4 * (rc - 2 * ROWU + 2 + i));
        }

#pragma unroll
        for (int j = 0; j < 8; ++j) {
            float ctr2 = 2.0f * C[j + 8];
            float dxx = (CB(X2Pa, j) + CB(x2m, j)) - ctr2;
            float dyy = (CB(Y2Pa, j) + CB(Y2Ma, j)) - ctr2;
            float dzz = (C[j + 2] + C[j + 14]) - ctr2;
            float dxy = (CB(PPn, j) - CB(Fpp, j)) - (CB(PMn, j) - CB(Fpm, j));
            float dxz = (CB(XPn, j + 7) - CB(Fxm, j + 7))
                      - (CB(XPn, j + 1) - CB(Fxm, j + 1));
            float dyz = (CB(YP4, j + 7) - CB(YM4, j + 7))
                      - (CB(YP4, j + 1) - CB(YM4, j + 1));
            float dd = dxx * dxx + dyy * dyy + dzz * dzz;
            float dc = dxy * dxy + dxz * dxz + dyz * dyz;
            float msk = (j >= jlo && j < jhi) ? 1.0f : 0.0f;
            e += msk * (dd + 2.0f * dc);
        }

        // rotate: x+1 data becomes x-1 data two steps later; x2m for s+1
#pragma unroll
        for (int i = 0; i < 4; ++i) Fxm[i] = XPn[i];
#pragma unroll
        for (int i = 0; i < 2; ++i) { Fpp[i] = PPn[i]; Fpm[i] = PMn[i]; }
        x2m[0] = sv0; x2m[1] = sv1;

        __syncthreads();   // drains stage vmcnt + orders slot reuse
    };

    for (int sp = 0; sp < 5; ++sp) {
        step(2 * sp,     true, fa_xm, fa_pp, fa_pm);
        step(2 * sp + 1, true, fb_xm, fb_pp, fb_pm);
    }
    step(10, true,  fa_xm, fa_pp, fa_pm);
    step(11, false, fb_xm, fb_pp, fb_pm);

    // wave reduce -> block reduce -> one atomic per block
#pragma unroll
    for (int off = 32; off > 0; off >>= 1) e += __shfl_down(e, off, 64);

    __shared__ float ws[4];
    int lane = tid & 63;
    int wid = tid >> 6;
    if (lane == 0) ws[wid] = e;
    __syncthreads();
    if (tid == 0) {
        // 0.0625 = (0.25)^2 from the two central-difference factors
        const float inv_count = 0.0625f / (156.0f * 156.0f * 156.0f * 3.0f);
        atomicAdd(&out[b], (ws[0] + ws[1] + ws[2] + ws[3]) * inv_count);
    }
}

extern "C" void kernel_launch(void* const* d_in, const int* in_sizes, int n_in,
                              void* d_out, int out_size, void* d_ws, size_t ws_size,
                              hipStream_t stream) {
    const float* f = (const float*)d_in[0];
    float* out = (float*)d_out;

    hipMemsetAsync(d_out, 0, out_size * sizeof(float), stream);

    be_kernel<<<dim3(NBLK), dim3(256), 0, stream>>>(f, out);
}

// Round 17
// 92.306 us; speedup vs baseline: 11.7706x; 1.6266x over previous
//
#include <hip/hip_runtime.h>

// BendingEnergy: fused 19-point stencil + per-batch mean, LDS x-march v13.
// = v12 (28 units/thread-step: v5's ping-pong reg FIFOs + x2m register-carry
// kills the slab x-2 read; 4-slot buffer, 47.6 KB -> 3 blocks/CU) with
// __launch_bounds__(256, 2): round-16 evidence says the allocator's VGPR cap
// is ~256/min_waves ((256,2)->128, (256,3)->85); v12's ~120-reg state needs
// the 128 cap, and LDS (not the bound) already limits occupancy to 3
// blocks/CU = 12 waves/CU.

typedef float F4 __attribute__((ext_vector_type(4)));

#define DIM 160
#define SX (DIM * DIM * 3)          // 76800
#define SY (DIM * 3)                // 480
#define FSZ ((long long)DIM * SX)
#define TOT (4LL * FSZ)

#define ROWS 20                     // staged y rows per slab (16 out + 4 halo)
#define ROWU 37                     // 16B units per row (36 used + 1 pad), ODD
#define USED_U (ROWS * ROWU)        // 740
#define SLICE_U 744                 // padded to mult of 8
#define SLICE_F (SLICE_U * 4)       // 2976 floats
#define SLOTS 4
#define STEPS 12
#define NSEG 13                     // 13 * 12 = 156
#define NMS 4                       // m segments (128 output floats each)
#define NYT 10                      // y tiles (16 rows each)
#define NBLK (4 * NSEG * NMS * NYT) // 2080
#define CPX (NBLK / 8)              // 260

#define CB(a, i) a[(i) >> 2][(i) & 3]

__global__ __launch_bounds__(256, 2) void be_kernel(const float* __restrict__ f,
                                                    float* __restrict__ out) {
    __shared__ float lds[SLICE_F * SLOTS];   // 47616 B -> 3 blocks/CU
    const int tid = threadIdx.x;

    // bijective XCD chunking; same-XCD blocks share (b, xseg) slab volumes
    int lid = (blockIdx.x & 7) * CPX + (blockIdx.x >> 3);
    int p2i = lid / (NMS * NYT);
    int q2i = lid % (NMS * NYT);
    int b = p2i / NSEG, xseg = p2i % NSEG;
    int ms = q2i / NYT, yt = q2i % NYT;

    const int X0 = 2 + xseg * STEPS;         // X0 % 4 == 2 always
    const int gy0 = 16 * yt;                 // first staged global y row
    const int core = 4 + 128 * ms;           // first output m of this segment
    const int Gm = core - 8;                 // staged m start (16B-aligned)
    const long long bb = (long long)b * FSZ;
    const float* fbase = f + bb;
    const float* fend = f + (TOT - 4);

    // lane remap (v5-proven): yy bit0 = tid bit3 -> bank-residue spread
    const int t = tid >> 4;                  // m-tile 0..15
    const int yy = ((tid >> 3) & 1) | ((tid & 7) << 1);  // y row 0..15
    const int m0 = core + 8 * t;
    const int y = 2 + 16 * yt + yy;

    int jlo = 6 - m0; if (jlo < 0) jlo = 0;  // valid m in [6, 474)
    int jhi = 474 - m0; if (jhi > 8) jhi = 8;
    if (y >= DIM - 2) jhi = -1;              // y edge mask

    // unit of (center row, m0-8); every LDS access is slot-base + rc + imm
    const int rc = (yy + 2) * ROWU + 2 * t;

    // stage chunk global offsets (fixed per thread)
    long long choff[3];
#pragma unroll
    for (int it = 0; it < 3; ++it) {
        int c = it * 256 + tid;
        int row = c / ROWU, col = c - row * ROWU;
        choff[it] = (long long)(gy0 + row) * SY + Gm + 4 * col;
    }
    const bool ch2ok = (512 + tid) < USED_U;

    auto stage = [&](int slab, int slot) {
        long long sb = (long long)slab * SX;
#pragma unroll
        for (int it = 0; it < 3; ++it) {
            if (it < 2 || ch2ok) {
                const float* gp = fbase + (sb + choff[it]);
                gp = gp < f ? f : gp;        // clamp buffer ends (masked data)
                gp = gp > fend ? fend : gp;
                __builtin_amdgcn_global_load_lds(
                    (const __attribute__((address_space(1))) unsigned int*)gp,
                    (__attribute__((address_space(3))) unsigned int*)
                        ((__attribute__((address_space(3))) float*)lds
                         + slot * SLICE_F + 4 * (it * 256 + tid)),
                    16, 0, 0);
            }
        }
    };

    // prologue: slabs X0-2..X0+1 -> slots 0..3 (X0 % 4 == 2)
    stage(X0 - 2, 0); stage(X0 - 1, 1); stage(X0, 2); stage(X0 + 1, 3);
    __syncthreads();

    // FIFO seeds (v5 pattern): set a consumed at even steps, b at odd.
    // fa_xm/fb_xm: units rc+1..4 (floats m0-4..m0+11) of slabs X0-1 / X0.
    // fa_pp/pm, fb_pp/pm: units rc+-ROWU+2..3 (floats m0..m0+7).
    // x2m: units rc+2..3 of slab X0-2 (X2M for step 0).
    F4 fa_xm[4], fa_pp[2], fa_pm[2], fb_xm[4], fb_pp[2], fb_pm[2], x2m[2];
    {
        const float* S1 = lds + 1 * SLICE_F;     // slab X0-1
        const float* S2 = lds + 2 * SLICE_F;     // slab X0
        const float* S0 = lds + 0 * SLICE_F;     // slab X0-2
#pragma unroll
        for (int i = 0; i < 4; ++i) {
            fa_xm[i] = *(const F4*)(S1 + 4 * (rc + 1 + i));
            fb_xm[i] = *(const F4*)(S2 + 4 * (rc + 1 + i));
        }
#pragma unroll
        for (int i = 0; i < 2; ++i) {
            fa_pp[i] = *(const F4*)(S1 + 4 * (rc + ROWU + 2 + i));
            fa_pm[i] = *(const F4*)(S1 + 4 * (rc - ROWU + 2 + i));
            fb_pp[i] = *(const F4*)(S2 + 4 * (rc + ROWU + 2 + i));
            fb_pm[i] = *(const F4*)(S2 + 4 * (rc - ROWU + 2 + i));
        }
        x2m[0] = *(const F4*)(S0 + 4 * (rc + 2));
        x2m[1] = *(const F4*)(S0 + 4 * (rc + 3));
    }
    __syncthreads();                 // seeds done before slot 0 reuse
    stage(X0 + 2, 0);                // slab X0+2 -> slot 0 (over X0-2)
    __syncthreads();                 // landed before step 0 reads it

    float e = 0.0f;                  // raw energy (x16 scale)

    // one x-step at s (x = X0+s); Fxm/Fpp/Fpm = this step's x-1 FIFO set
    // (overwritten with x+1 data); x2m = slab x-2 middles, updated from Fxm.
    auto step = [&](int s, bool do_stage, F4* Fxm, F4* Fpp, F4* Fpm) {
        F4 sv0 = Fxm[1], sv1 = Fxm[2];       // slab x-1 -> X2M of step s+1
        if (do_stage) stage(X0 + s + 3, (s + 1) & 3);

        const float* Lx  = lds + ((s + 2) & 3) * SLICE_F;  // slab x
        const float* Lx1 = lds + ((s + 3) & 3) * SLICE_F;  // slab x+1
        const float* Lx2 = lds + ((s) & 3) * SLICE_F;      // slab x+2

        float C[24];
        F4 XPn[4], PPn[2], PMn[2], YP4[4], YM4[4], X2Pa[2], Y2Pa[2], Y2Ma[2];
        // C: units rc..rc+5 (floats m0-8..m0+15), slab x
#pragma unroll
        for (int i = 0; i < 6; ++i)
            *(F4*)(&C[4 * i]) = *(const F4*)(Lx + 4 * (rc + i));
        // fresh x+1 row (floats m0-4..m0+11) + diagonals (floats m0..m0+7)
#pragma unroll
        for (int i = 0; i < 4; ++i) {
            XPn[i] = *(const F4*)(Lx1 + 4 * (rc + 1 + i));
            YP4[i] = *(const F4*)(Lx + 4 * (rc + ROWU + 1 + i));
            YM4[i] = *(const F4*)(Lx + 4 * (rc - ROWU + 1 + i));
        }
#pragma unroll
        for (int i = 0; i < 2; ++i) {
            PPn[i]  = *(const F4*)(Lx1 + 4 * (rc + ROWU + 2 + i));
            PMn[i]  = *(const F4*)(Lx1 + 4 * (rc - ROWU + 2 + i));
            X2Pa[i] = *(const F4*)(Lx2 + 4 * (rc + 2 + i));
            Y2Pa[i] = *(const F4*)(Lx + 4 * (rc + 2 * ROWU + 2 + i));
            Y2Ma[i] = *(const F4*)(Lx + 4 * (rc - 2 * ROWU + 2 + i));
        }

#pragma unroll
        for (int j = 0; j < 8; ++j) {
            float ctr2 = 2.0f * C[j + 8];
            float dxx = (CB(X2Pa, j) + CB(x2m, j)) - ctr2;
            float dyy = (CB(Y2Pa, j) + CB(Y2Ma, j)) - ctr2;
            float dzz = (C[j + 2] + C[j + 14]) - ctr2;
            float dxy = (CB(PPn, j) - CB(Fpp, j)) - (CB(PMn, j) - CB(Fpm, j));
            float dxz = (CB(XPn, j + 7) - CB(Fxm, j + 7))
                      - (CB(XPn, j + 1) - CB(Fxm, j + 1));
            float dyz = (CB(YP4, j + 7) - CB(YM4, j + 7))
                      - (CB(YP4, j + 1) - CB(YM4, j + 1));
            float dd = dxx * dxx + dyy * dyy + dzz * dzz;
            float dc = dxy * dxy + dxz * dxz + dyz * dyz;
            float msk = (j >= jlo && j < jhi) ? 1.0f : 0.0f;
            e += msk * (dd + 2.0f * dc);
        }

        // rotate: x+1 data becomes x-1 data two steps later; x2m for s+1
#pragma unroll
        for (int i = 0; i < 4; ++i) Fxm[i] = XPn[i];
#pragma unroll
        for (int i = 0; i < 2; ++i) { Fpp[i] = PPn[i]; Fpm[i] = PMn[i]; }
        x2m[0] = sv0; x2m[1] = sv1;

        __syncthreads();   // drains stage vmcnt + orders slot reuse
    };

    for (int sp = 0; sp < 5; ++sp) {
        step(2 * sp,     true, fa_xm, fa_pp, fa_pm);
        step(2 * sp + 1, true, fb_xm, fb_pp, fb_pm);
    }
    step(10, true,  fa_xm, fa_pp, fa_pm);
    step(11, false, fb_xm, fb_pp, fb_pm);

    // wave reduce -> block reduce -> one atomic per block
#pragma unroll
    for (int off = 32; off > 0; off >>= 1) e += __shfl_down(e, off, 64);

    __shared__ float ws[4];
    int lane = tid & 63;
    int wid = tid >> 6;
    if (lane == 0) ws[wid] = e;
    __syncthreads();
    if (tid == 0) {
        // 0.0625 = (0.25)^2 from the two central-difference factors
        const float inv_count = 0.0625f / (156.0f * 156.0f * 156.0f * 3.0f);
        atomicAdd(&out[b], (ws[0] + ws[1] + ws[2] + ws[3]) * inv_count);
    }
}

extern "C" void kernel_launch(void* const* d_in, const int* in_sizes, int n_in,
                              void* d_out, int out_size, void* d_ws, size_t ws_size,
                              hipStream_t stream) {
    const float* f = (const float*)d_in[0];
    float* out = (float*)d_out;

    hipMemsetAsync(d_out, 0, out_size * sizeof(float), stream);

    be_kernel<<<dim3(NBLK), dim3(256), 0, stream>>>(f, out);
}